// Round 1
// baseline (267.569 us; speedup 1.0000x reference)
//
#include <hip/hip_runtime.h>
#include <cstdint>

#define TSTEPS 120

// ---------------- Threefry-2x32 (JAX/Random123), 20 rounds ----------------
__device__ __forceinline__ uint32_t rotl32(uint32_t x, uint32_t r) {
    return (x << r) | (x >> (32u - r));
}

__device__ __forceinline__ void tf2x32(uint32_t ks0, uint32_t ks1, uint32_t ks2,
                                       uint32_t x0, uint32_t x1,
                                       uint32_t &o0, uint32_t &o1) {
    x0 += ks0; x1 += ks1;
#define TF_R(r) { x0 += x1; x1 = rotl32(x1, r); x1 ^= x0; }
    TF_R(13u) TF_R(15u) TF_R(26u) TF_R(6u)
    x0 += ks1; x1 += ks2 + 1u;
    TF_R(17u) TF_R(29u) TF_R(16u) TF_R(24u)
    x0 += ks2; x1 += ks0 + 2u;
    TF_R(13u) TF_R(15u) TF_R(26u) TF_R(6u)
    x0 += ks0; x1 += ks1 + 3u;
    TF_R(17u) TF_R(29u) TF_R(16u) TF_R(24u)
    x0 += ks1; x1 += ks2 + 4u;
    TF_R(13u) TF_R(15u) TF_R(26u) TF_R(6u)
    x0 += ks2; x1 += ks0 + 5u;
#undef TF_R
    o0 = x0; o1 = x1;
}

// ---------------- XLA ErfInv (f32, Giles 2012 polynomial) ----------------
__device__ __forceinline__ float erfinv_xla(float x) {
    float w = -log1pf(-x * x);
    float p;
    if (w < 5.0f) {
        w = w - 2.5f;
        p = 2.81022636e-08f;
        p = fmaf(p, w, 3.43273939e-07f);
        p = fmaf(p, w, -3.5233877e-06f);
        p = fmaf(p, w, -4.39150654e-06f);
        p = fmaf(p, w, 0.00021858087f);
        p = fmaf(p, w, -0.00125372503f);
        p = fmaf(p, w, -0.00417768164f);
        p = fmaf(p, w, 0.246640727f);
        p = fmaf(p, w, 1.50140941f);
    } else {
        w = sqrtf(w) - 3.0f;
        p = -0.000200214257f;
        p = fmaf(p, w, 0.000100950558f);
        p = fmaf(p, w, 0.00134934322f);
        p = fmaf(p, w, -0.00367342844f);
        p = fmaf(p, w, 0.00573950773f);
        p = fmaf(p, w, -0.0076224613f);
        p = fmaf(p, w, 0.00943887047f);
        p = fmaf(p, w, 1.00167406f);
        p = fmaf(p, w, 2.83297682f);
    }
    return p * x;
}

// jax.nn.softplus(x) == jnp.logaddexp(x, 0) == max(x,0) + log1p(exp(-|x|))
__device__ __forceinline__ float softplus_f(float x) {
    return fmaxf(x, 0.0f) + log1pf(expf(-fabsf(x)));
}

__global__ __launch_bounds__(256) void accrace_kernel(
    const float* __restrict__ logits,
    const float* __restrict__ g_input_scale,
    const float* __restrict__ g_leak,
    const float* __restrict__ g_se,
    const float* __restrict__ g_inhib,
    const float* __restrict__ g_nstd,
    const float* __restrict__ g_ew,
    const float* __restrict__ g_eb,
    float* __restrict__ out, int n)
{
    // ---- per-block: compute the 120 split keys (partitionable semantics):
    // keys[t] = threefry2x32((0,42), (0,t)), both output words form the key.
    __shared__ uint32_t kw0[TSTEPS], kw1[TSTEPS];
    const int tid = threadIdx.x;
    if (tid < TSTEPS) {
        uint32_t o0, o1;
        const uint32_t k0 = 0u, k1 = 42u;  // jax.random.key(42)
        tf2x32(k0, k1, k0 ^ k1 ^ 0x1BD11BDAu, 0u, (uint32_t)tid, o0, o1);
        kw0[tid] = o0; kw1[tid] = o1;
    }
    __syncthreads();

    const int j = blockIdx.x * blockDim.x + tid;   // flat (b,c) index
    if (j >= n) return;
    const int c = j & 3;

    // ---- parameters (softplus transforms) ----
    const float input_scale = g_input_scale[0];
    const float lkc   = softplus_f(g_leak[c]);
    const float sec   = softplus_f(g_se[c]);
    const float inhib = softplus_f(g_inhib[0]);
    const float nstd  = softplus_f(g_nstd[0]);
    const float ew = g_ew[0], eb = g_eb[0];

    // ---- evidence: scale, center over C (4-lane butterfly), softplus, 1x1 linear
    const float xs = logits[j] * input_scale;
    const float s01  = xs + __shfl_xor(xs, 1, 64);
    const float s    = s01 + __shfl_xor(s01, 2, 64);
    const float mean = s * 0.25f;                 // /4 is exact
    const float evd  = softplus_f(xs - mean) * ew + eb;

    // ---- uniform->normal constants (match jax._src.random._uniform/_normal_real)
    const float LO    = -0.99999994f;                // nextafter(-1,0) f32
    const float RANGE = 1.0f - LO;                   // rounds to 2.0f, same as XLA
    const float SQRT2 = 1.41421356237309515f;        // f32(0x3FB504F3)

    float acc = 0.0f, diffc = 0.0f, slope = 0.0f;
    int idx = -1;
    const uint32_t jj = (uint32_t)j;

    for (int t = 0; t < TSTEPS; ++t) {
        const uint32_t k0 = kw0[t], k1 = kw1[t];
        const uint32_t ks2 = k0 ^ k1 ^ 0x1BD11BDAu;

        // total over the 4 classes of this row (exact commutative tree)
        const float sa    = acc + __shfl_xor(acc, 1, 64);
        const float total = sa + __shfl_xor(sa, 2, 64);

        // noise bits: partitionable random_bits -> block (0, j), fold o0^o1
        uint32_t o0, o1;
        tf2x32(k0, k1, ks2, 0u, jj, o0, o1);
        const uint32_t bits = o0 ^ o1;

        const float f = __uint_as_float((bits >> 9) | 0x3F800000u) - 1.0f;  // [0,1)
        const float u = fmaxf(LO, f * RANGE + LO);                          // (-1,1)
        const float noise = (SQRT2 * erfinv_xla(u)) * nstd;

        const float total_other = total - acc;
        const float drive = evd + sec * acc - inhib * total_other - lkc * acc;
        const float ds   = softplus_f(drive + noise) - acc;
        const float accn = fmaxf(acc + 0.2f * ds, 0.0f);

        if (idx < 0 && accn > 0.5f) {       // first threshold crossing
            idx = t; diffc = accn - 0.5f; slope = 0.2f * ds;
        }
        acc = accn;
    }

    float o;
    if (idx >= 0) {
        const float ss = (slope >= 0.0f) ? fmaxf(slope, 1e-3f) : fminf(slope, -1e-3f);
        const float tc = (float)idx - diffc / ss;
        o = (tc * 10.0f) / 1000.0f;         // * DT, then ms -> s
    } else {
        o = 1200.0f / 1000.0f;              // never crossed: T_STEPS * DT ms
    }
    out[j] = o;
}

extern "C" void kernel_launch(void* const* d_in, const int* in_sizes, int n_in,
                              void* d_out, int out_size, void* d_ws, size_t ws_size,
                              hipStream_t stream) {
    const float* logits       = (const float*)d_in[0];
    const float* input_scale  = (const float*)d_in[1];
    const float* leak         = (const float*)d_in[2];
    const float* self_excit   = (const float*)d_in[3];
    const float* inhibition   = (const float*)d_in[4];
    // d_in[5] = competition_gain: unused (MIX == 0.0 in reference)
    const float* noise_std    = (const float*)d_in[6];
    const float* evidence_w   = (const float*)d_in[7];
    const float* evidence_b   = (const float*)d_in[8];

    const int n = in_sizes[0];              // B*C = 262144
    const int threads = 256;
    const int blocks = (n + threads - 1) / threads;
    accrace_kernel<<<blocks, threads, 0, stream>>>(
        logits, input_scale, leak, self_excit, inhibition,
        noise_std, evidence_w, evidence_b, (float*)d_out, n);
}

// Round 2
// 102.653 us; speedup vs baseline: 2.6065x; 2.6065x over previous
//
#include <hip/hip_runtime.h>
#include <cstdint>

#define TSTEPS 120

__device__ __forceinline__ uint32_t rotl32(uint32_t x, uint32_t r) {
    return (x << r) | (x >> (32u - r));
}

// Threefry-2x32, 20 rounds, two independent counters (0,xa1) and (0,xb1),
// folded output o0^o1 (JAX partitionable random_bits semantics).
__device__ __forceinline__ void tf2x32_pair(uint32_t ks0, uint32_t ks1, uint32_t ks2,
                                            uint32_t xa1, uint32_t xb1,
                                            uint32_t &oa, uint32_t &ob) {
    uint32_t a0 = ks0, a1 = xa1 + ks1;
    uint32_t b0 = ks0, b1 = xb1 + ks1;
#define R2(r) { a0 += a1; a1 = rotl32(a1, r); a1 ^= a0; \
                b0 += b1; b1 = rotl32(b1, r); b1 ^= b0; }
    R2(13u) R2(15u) R2(26u) R2(6u)
    a0 += ks1; a1 += ks2 + 1u;  b0 += ks1; b1 += ks2 + 1u;
    R2(17u) R2(29u) R2(16u) R2(24u)
    a0 += ks2; a1 += ks0 + 2u;  b0 += ks2; b1 += ks0 + 2u;
    R2(13u) R2(15u) R2(26u) R2(6u)
    a0 += ks0; a1 += ks1 + 3u;  b0 += ks0; b1 += ks1 + 3u;
    R2(17u) R2(29u) R2(16u) R2(24u)
    a0 += ks1; a1 += ks2 + 4u;  b0 += ks1; b1 += ks2 + 4u;
    R2(13u) R2(15u) R2(26u) R2(6u)
    a0 += ks2; a1 += ks0 + 5u;  b0 += ks2; b1 += ks0 + 5u;
#undef R2
    oa = a0 ^ a1; ob = b0 ^ b1;
}

// softplus(x) = max(x,0) + log1p(exp(-|x|)); raw v_exp_f32 / v_log_f32.
// 1+e is exact (Sterbenz) for e>=0.5 region of interest; <=2ulp elsewhere.
__device__ __forceinline__ float softplus_fast(float x) {
    const float LOG2E = 1.4426950408889634f;
    const float LN2   = 0.6931471805599453f;
    float e = __builtin_amdgcn_exp2f(-fabsf(x) * LOG2E);
    float l = __builtin_amdgcn_logf(1.0f + e) * LN2;
    return fmaxf(x, 0.0f) + l;
}

// XLA ErfInv (Giles poly), branchless: both paths evaluated, cndmask select.
__device__ __forceinline__ float erfinv_fast(float x) {
    const float LN2 = 0.6931471805599453f;
    float t = 1.0f - x * x;                      // |t|>=0.5 path is Sterbenz-exact
    float w = -(__builtin_amdgcn_logf(t) * LN2); // == -log1p(-x*x) to ~2ulp
    float wa = w - 2.5f;
    float wb = __builtin_amdgcn_sqrtf(w) - 3.0f;
    float pa = 2.81022636e-08f, pb = -0.000200214257f;
    pa = fmaf(pa, wa, 3.43273939e-07f);  pb = fmaf(pb, wb, 0.000100950558f);
    pa = fmaf(pa, wa, -3.5233877e-06f);  pb = fmaf(pb, wb, 0.00134934322f);
    pa = fmaf(pa, wa, -4.39150654e-06f); pb = fmaf(pb, wb, -0.00367342844f);
    pa = fmaf(pa, wa, 0.00021858087f);   pb = fmaf(pb, wb, 0.00573950773f);
    pa = fmaf(pa, wa, -0.00125372503f);  pb = fmaf(pb, wb, -0.0076224613f);
    pa = fmaf(pa, wa, -0.00417768164f);  pb = fmaf(pb, wb, 0.00943887047f);
    pa = fmaf(pa, wa, 0.246640727f);     pb = fmaf(pb, wb, 1.00167406f);
    pa = fmaf(pa, wa, 1.50140941f);      pb = fmaf(pb, wb, 2.83297682f);
    float p = (w < 5.0f) ? pa : pb;
    return p * x;
}

__global__ __launch_bounds__(256) void accrace_kernel(
    const float* __restrict__ logits,
    const float* __restrict__ g_input_scale,
    const float* __restrict__ g_leak,
    const float* __restrict__ g_se,
    const float* __restrict__ g_inhib,
    const float* __restrict__ g_nstd,
    const float* __restrict__ g_ew,
    const float* __restrict__ g_eb,
    float* __restrict__ out, int n)
{
    // split keys: keys[t] = threefry2x32((0,42), (0,t)), both words.
    __shared__ uint32_t kw0[TSTEPS], kw1[TSTEPS];
    const int tid = threadIdx.x;
    if (tid < TSTEPS) {
        uint32_t o0, o1;
        const uint32_t k0 = 0u, k1 = 42u;
        uint32_t x0 = 0u, x1 = (uint32_t)tid;
        uint32_t ks2 = k0 ^ k1 ^ 0x1BD11BDAu;
        x0 += k0; x1 += k1;
#define TF_R(r) { x0 += x1; x1 = rotl32(x1, r); x1 ^= x0; }
        TF_R(13u) TF_R(15u) TF_R(26u) TF_R(6u)
        x0 += k1; x1 += ks2 + 1u;
        TF_R(17u) TF_R(29u) TF_R(16u) TF_R(24u)
        x0 += ks2; x1 += k0 + 2u;
        TF_R(13u) TF_R(15u) TF_R(26u) TF_R(6u)
        x0 += k0; x1 += k1 + 3u;
        TF_R(17u) TF_R(29u) TF_R(16u) TF_R(24u)
        x0 += k1; x1 += ks2 + 4u;
        TF_R(13u) TF_R(15u) TF_R(26u) TF_R(6u)
        x0 += ks2; x1 += k0 + 5u;
#undef TF_R
        kw0[tid] = x0; kw1[tid] = x1;
    }
    __syncthreads();

    // ILP2: this thread owns elements jA = base+tid and jB = base+256+tid.
    const int base = blockIdx.x * 512;
    const int jA = base + tid;
    const int jB = base + 256 + tid;
    if (jB >= n) return;                 // n % 512 == 0 in practice
    const int c = tid & 3;               // same for both (256 % 4 == 0)

    const float input_scale = g_input_scale[0];
    const float lkc   = softplus_fast(g_leak[c]);
    const float sec   = softplus_fast(g_se[c]);
    const float inhib = softplus_fast(g_inhib[0]);
    const float nstd  = softplus_fast(g_nstd[0]);
    const float ew = g_ew[0], eb = g_eb[0];

    // evidence for both elements (4-lane butterfly mean over classes)
    const float xsA = logits[jA] * input_scale;
    const float xsB = logits[jB] * input_scale;
    const float sA1 = xsA + __shfl_xor(xsA, 1, 64);
    const float sB1 = xsB + __shfl_xor(xsB, 1, 64);
    const float sA  = sA1 + __shfl_xor(sA1, 2, 64);
    const float sB  = sB1 + __shfl_xor(sB1, 2, 64);
    const float evdA = softplus_fast(xsA - sA * 0.25f) * ew + eb;
    const float evdB = softplus_fast(xsB - sB * 0.25f) * ew + eb;

    const float LO    = -0.99999994f;    // nextafter(-1,0)
    const float RANGE = 2.0f;            // f32(1 - LO)
    const float SQRT2 = 1.41421356237309515f;

    float accA = 0.0f, diffA = 0.0f, slopeA = 0.0f;
    float accB = 0.0f, diffB = 0.0f, slopeB = 0.0f;
    int idxA = -1, idxB = -1;
    const uint32_t ctrA = (uint32_t)jA, ctrB = (uint32_t)jB;

    // software-pipelined threefry: bits for step t computed during step t-1
    uint32_t nbA, nbB;
    {
        const uint32_t k0 = kw0[0], k1 = kw1[0];
        tf2x32_pair(k0, k1, k0 ^ k1 ^ 0x1BD11BDAu, ctrA, ctrB, nbA, nbB);
    }

    for (int t = 0; t < TSTEPS; ++t) {
        const uint32_t bitsA = nbA, bitsB = nbB;
        if (t + 1 < TSTEPS) {
            const uint32_t k0 = kw0[t + 1], k1 = kw1[t + 1];
            tf2x32_pair(k0, k1, k0 ^ k1 ^ 0x1BD11BDAu, ctrA, ctrB, nbA, nbB);
        }

        // per-row totals (exact commutative 4-lane tree)
        const float tA1 = accA + __shfl_xor(accA, 1, 64);
        const float tB1 = accB + __shfl_xor(accB, 1, 64);
        const float totA = tA1 + __shfl_xor(tA1, 2, 64);
        const float totB = tB1 + __shfl_xor(tB1, 2, 64);

        const float fA = __uint_as_float((bitsA >> 9) | 0x3F800000u) - 1.0f;
        const float fB = __uint_as_float((bitsB >> 9) | 0x3F800000u) - 1.0f;
        const float uA = fmaxf(LO, fA * RANGE + LO);
        const float uB = fmaxf(LO, fB * RANGE + LO);
        const float nzA = (SQRT2 * erfinv_fast(uA)) * nstd;
        const float nzB = (SQRT2 * erfinv_fast(uB)) * nstd;

        const float toA = totA - accA;
        const float toB = totB - accB;
        const float drA = evdA + sec * accA - inhib * toA - lkc * accA;
        const float drB = evdB + sec * accB - inhib * toB - lkc * accB;
        const float dsA = softplus_fast(drA + nzA) - accA;
        const float dsB = softplus_fast(drB + nzB) - accB;
        const float anA = fmaxf(accA + 0.2f * dsA, 0.0f);
        const float anB = fmaxf(accB + 0.2f * dsB, 0.0f);

        const bool crA = (idxA < 0) && (anA > 0.5f);
        const bool crB = (idxB < 0) && (anB > 0.5f);
        idxA   = crA ? t : idxA;            idxB   = crB ? t : idxB;
        diffA  = crA ? anA - 0.5f : diffA;  diffB  = crB ? anB - 0.5f : diffB;
        slopeA = crA ? 0.2f * dsA : slopeA; slopeB = crB ? 0.2f * dsB : slopeB;
        accA = anA; accB = anB;
    }

    float oA, oB;
    if (idxA >= 0) {
        const float ss = (slopeA >= 0.0f) ? fmaxf(slopeA, 1e-3f) : fminf(slopeA, -1e-3f);
        oA = (((float)idxA - diffA / ss) * 10.0f) / 1000.0f;
    } else oA = 1.2f;
    if (idxB >= 0) {
        const float ss = (slopeB >= 0.0f) ? fmaxf(slopeB, 1e-3f) : fminf(slopeB, -1e-3f);
        oB = (((float)idxB - diffB / ss) * 10.0f) / 1000.0f;
    } else oB = 1.2f;
    out[jA] = oA;
    out[jB] = oB;
}

extern "C" void kernel_launch(void* const* d_in, const int* in_sizes, int n_in,
                              void* d_out, int out_size, void* d_ws, size_t ws_size,
                              hipStream_t stream) {
    const float* logits       = (const float*)d_in[0];
    const float* input_scale  = (const float*)d_in[1];
    const float* leak         = (const float*)d_in[2];
    const float* self_excit   = (const float*)d_in[3];
    const float* inhibition   = (const float*)d_in[4];
    // d_in[5] = competition_gain: unused (MIX == 0.0)
    const float* noise_std    = (const float*)d_in[6];
    const float* evidence_w   = (const float*)d_in[7];
    const float* evidence_b   = (const float*)d_in[8];

    const int n = in_sizes[0];              // B*C = 262144
    const int threads = 256;
    const int blocks = (n + 2 * threads - 1) / (2 * threads);
    accrace_kernel<<<blocks, threads, 0, stream>>>(
        logits, input_scale, leak, self_excit, inhibition,
        noise_std, evidence_w, evidence_b, (float*)d_out, n);
}

// Round 6
// 93.634 us; speedup vs baseline: 2.8576x; 1.0963x over previous
//
#include <hip/hip_runtime.h>
#include <cstdint>

#define TSTEPS 120

typedef float f32x2 __attribute__((ext_vector_type(2)));
typedef unsigned int u32;

__device__ __forceinline__ u32 rotl32(u32 x, u32 r) { return (x << r) | (x >> (32u - r)); }

__device__ __forceinline__ f32x2 splat2(float v) { f32x2 r; r.x = v; r.y = v; return r; }
__device__ __forceinline__ f32x2 fma2(f32x2 a, f32x2 b, f32x2 c) {
    return __builtin_elementwise_fma(a, b, c);
}

// Exact 4-lane butterflies via DPP quad_perm (no LDS, no DS pipe).
// [1,0,3,2] = 0xB1 (xor 1), [2,3,0,1] = 0x4E (xor 2).
__device__ __forceinline__ float qxor1(float x) {
    return __int_as_float(__builtin_amdgcn_update_dpp(0, __float_as_int(x), 0xB1, 0xF, 0xF, true));
}
__device__ __forceinline__ float qxor2(float x) {
    return __int_as_float(__builtin_amdgcn_update_dpp(0, __float_as_int(x), 0x4E, 0xF, 0xF, true));
}

// softplus(x) = max(x,0) + log1p(exp(-|x|)) via raw v_exp/v_log
__device__ __forceinline__ float softplus_s(float x) {
    const float LOG2E = 1.4426950408889634f, LN2 = 0.6931471805599453f;
    float e = __builtin_amdgcn_exp2f(-fabsf(x) * LOG2E);
    return fmaxf(x, 0.0f) + __builtin_amdgcn_logf(1.0f + e) * LN2;
}

__device__ __forceinline__ f32x2 softplus2(f32x2 x) {
    const float LOG2E = 1.4426950408889634f, LN2 = 0.6931471805599453f;
    f32x2 t = __builtin_elementwise_abs(x) * splat2(-LOG2E);
    f32x2 e; e.x = __builtin_amdgcn_exp2f(t.x); e.y = __builtin_amdgcn_exp2f(t.y);
    f32x2 e1 = e + splat2(1.0f);
    f32x2 l; l.x = __builtin_amdgcn_logf(e1.x); l.y = __builtin_amdgcn_logf(e1.y);
    f32x2 mx = __builtin_elementwise_max(x, splat2(0.0f));
    return fma2(l, splat2(LN2), mx);
}

// XLA ErfInv (Giles), packed; rare |x|>0.99665 tail behind a wave-uniform branch.
__device__ __forceinline__ f32x2 erfinv2(f32x2 x) {
    const float LN2 = 0.6931471805599453f;
    f32x2 t = fma2(-x, x, splat2(1.0f));
    f32x2 w;
    w.x = __builtin_amdgcn_logf(t.x) * (-LN2);
    w.y = __builtin_amdgcn_logf(t.y) * (-LN2);
    f32x2 wa = w - splat2(2.5f);
    f32x2 p = splat2(2.81022636e-08f);
    p = fma2(p, wa, splat2(3.43273939e-07f));
    p = fma2(p, wa, splat2(-3.5233877e-06f));
    p = fma2(p, wa, splat2(-4.39150654e-06f));
    p = fma2(p, wa, splat2(0.00021858087f));
    p = fma2(p, wa, splat2(-0.00125372503f));
    p = fma2(p, wa, splat2(-0.00417768164f));
    p = fma2(p, wa, splat2(0.246640727f));
    p = fma2(p, wa, splat2(1.50140941f));
    if (__any((w.x >= 5.0f) || (w.y >= 5.0f))) {
        f32x2 wb;
        wb.x = __builtin_amdgcn_sqrtf(w.x) - 3.0f;
        wb.y = __builtin_amdgcn_sqrtf(w.y) - 3.0f;
        f32x2 q = splat2(-0.000200214257f);
        q = fma2(q, wb, splat2(0.000100950558f));
        q = fma2(q, wb, splat2(0.00134934322f));
        q = fma2(q, wb, splat2(-0.00367342844f));
        q = fma2(q, wb, splat2(0.00573950773f));
        q = fma2(q, wb, splat2(-0.0076224613f));
        q = fma2(q, wb, splat2(0.00943887047f));
        q = fma2(q, wb, splat2(1.00167406f));
        q = fma2(q, wb, splat2(2.83297682f));
        p.x = (w.x < 5.0f) ? p.x : q.x;
        p.y = (w.y < 5.0f) ? p.y : q.y;
    }
    return p * x;
}

// Threefry-2x32, 20 rounds, counters (0,cA),(0,cB), folded o0^o1.
// k0,k1 are wave-uniform (readfirstlane'd) -> key schedule runs on SALU.
__device__ __forceinline__ void tf_pair(u32 k0, u32 k1, u32 cA, u32 cB, u32 &oa, u32 &ob) {
    const u32 ks2 = k0 ^ k1 ^ 0x1BD11BDAu;
    const u32 i1 = ks2 + 1u, i2 = k0 + 2u, i3 = k1 + 3u, i4 = ks2 + 4u, i5 = k0 + 5u;
    u32 a0 = k0, a1 = cA + k1;
    u32 b0 = k0, b1 = cB + k1;
#define R2(r) { a0 += a1; a1 = rotl32(a1,(r)); a1 ^= a0; \
                b0 += b1; b1 = rotl32(b1,(r)); b1 ^= b0; }
    R2(13u) R2(15u) R2(26u) R2(6u)
    a0 += k1;  a1 += i1;  b0 += k1;  b1 += i1;
    R2(17u) R2(29u) R2(16u) R2(24u)
    a0 += ks2; a1 += i2;  b0 += ks2; b1 += i2;
    R2(13u) R2(15u) R2(26u) R2(6u)
    a0 += k0;  a1 += i3;  b0 += k0;  b1 += i3;
    R2(17u) R2(29u) R2(16u) R2(24u)
    a0 += k1;  a1 += i4;  b0 += k1;  b1 += i4;
    R2(13u) R2(15u) R2(26u) R2(6u)
    a0 += ks2; a1 += i5;  b0 += ks2; b1 += i5;
#undef R2
    oa = a0 ^ a1; ob = b0 ^ b1;
}

__global__ __launch_bounds__(256) void accrace_kernel(
    const float* __restrict__ logits,
    const float* __restrict__ g_input_scale,
    const float* __restrict__ g_leak,
    const float* __restrict__ g_se,
    const float* __restrict__ g_inhib,
    const float* __restrict__ g_nstd,
    const float* __restrict__ g_ew,
    const float* __restrict__ g_eb,
    float* __restrict__ out, int n)
{
    // split keys: keys[t] = threefry2x32((0,42),(0,t)), both words
    __shared__ u32 kw0[TSTEPS], kw1[TSTEPS];
    const int tid = threadIdx.x;
    if (tid < TSTEPS) {
        const u32 k0 = 0u, k1 = 42u;
        const u32 ks2 = k0 ^ k1 ^ 0x1BD11BDAu;
        u32 x0 = k0, x1 = (u32)tid + k1;
#define TF_R(r) { x0 += x1; x1 = rotl32(x1,(r)); x1 ^= x0; }
        TF_R(13u) TF_R(15u) TF_R(26u) TF_R(6u)
        x0 += k1;  x1 += ks2 + 1u;
        TF_R(17u) TF_R(29u) TF_R(16u) TF_R(24u)
        x0 += ks2; x1 += k0 + 2u;
        TF_R(13u) TF_R(15u) TF_R(26u) TF_R(6u)
        x0 += k0;  x1 += k1 + 3u;
        TF_R(17u) TF_R(29u) TF_R(16u) TF_R(24u)
        x0 += k1;  x1 += ks2 + 4u;
        TF_R(13u) TF_R(15u) TF_R(26u) TF_R(6u)
        x0 += ks2; x1 += k0 + 5u;
#undef TF_R
        kw0[tid] = x0; kw1[tid] = x1;
    }
    __syncthreads();

    const int base = blockIdx.x * 512;
    const int jA = base + tid;
    const int jB = base + 256 + tid;
    if (jB >= n) return;                  // n % 512 == 0
    const int c = tid & 3;

    const float input_scale = g_input_scale[0];
    const float lkc   = softplus_s(g_leak[c]);
    const float sec   = softplus_s(g_se[c]);
    const float inhib = softplus_s(g_inhib[0]);
    const float nstd  = softplus_s(g_nstd[0]);
    const float ew = g_ew[0], eb = g_eb[0];

    const float gain   = sec + inhib - lkc;                 // drive fold
    const float minhib = -inhib;
    const float SQ2N   = 1.41421356237309515f * nstd;       // noise fold
    const float LO     = -0.99999994f;

    // evidence (same exact 4-lane tree as before, via DPP)
    const float xsA = logits[jA] * input_scale;
    const float xsB = logits[jB] * input_scale;
    float mA = xsA + qxor1(xsA); mA = (mA + qxor2(mA)) * 0.25f;
    float mB = xsB + qxor1(xsB); mB = (mB + qxor2(mB)) * 0.25f;
    f32x2 evd; evd.x = softplus_s(xsA - mA) * ew + eb;
               evd.y = softplus_s(xsB - mB) * ew + eb;

    const u32 ctrA = (u32)jA, ctrB = (u32)jB;

    u32 nbA, nbB;
    {
        u32 k0 = (u32)__builtin_amdgcn_readfirstlane((int)kw0[0]);
        u32 k1 = (u32)__builtin_amdgcn_readfirstlane((int)kw1[0]);
        tf_pair(k0, k1, ctrA, ctrB, nbA, nbB);
    }
    u32 pk0 = kw0[1], pk1 = kw1[1];       // prefetched keys (t+1)

    f32x2 acc = splat2(0.0f);
    f32x2 tfx = splat2(-1.0f);            // crossing step (float), -1 = not yet
    f32x2 dfx = splat2(0.0f);             // acc value at crossing
    f32x2 slx = splat2(0.0f);             // raw ds at crossing
    float tcur = 0.0f;

#pragma unroll 2
    for (int t = 0; t < TSTEPS; ++t) {
        const u32 bitsA = nbA, bitsB = nbB;
        {   // next-step bits (independent chain; wasted once at t=119)
            u32 k0 = (u32)__builtin_amdgcn_readfirstlane((int)pk0);
            u32 k1 = (u32)__builtin_amdgcn_readfirstlane((int)pk1);
            tf_pair(k0, k1, ctrA, ctrB, nbA, nbB);
        }
        const int tn2 = (t + 2 < TSTEPS) ? t + 2 : TSTEPS - 1;
        pk0 = kw0[tn2]; pk1 = kw1[tn2];

        // per-row totals (exact 4-lane tree via DPP)
        f32x2 s1, tot;
        s1.x = acc.x + qxor1(acc.x);  s1.y = acc.y + qxor1(acc.y);
        tot.x = s1.x + qxor2(s1.x);   tot.y = s1.y + qxor2(s1.y);

        // bits -> uniform(-1,1) -> normal
        f32x2 fr;
        fr.x = __uint_as_float((bitsA >> 9) | 0x3F800000u);
        fr.y = __uint_as_float((bitsB >> 9) | 0x3F800000u);
        f32x2 f = fr - splat2(1.0f);
        f32x2 u = __builtin_elementwise_max(fma2(f, splat2(2.0f), splat2(LO)), splat2(LO));
        f32x2 nz = erfinv2(u) * splat2(SQ2N);

        // drive = evd + gain*acc - inhib*tot ; ds = softplus(drive+nz) - acc
        f32x2 dr = fma2(acc, splat2(gain), fma2(tot, splat2(minhib), evd));
        f32x2 ds = softplus2(dr + nz) - acc;
        f32x2 an = __builtin_elementwise_max(fma2(ds, splat2(0.2f), acc), splat2(0.0f));

        const bool cA = (tfx.x < 0.0f) && (an.x > 0.5f);
        const bool cB = (tfx.y < 0.0f) && (an.y > 0.5f);
        tfx.x = cA ? tcur : tfx.x;  dfx.x = cA ? an.x : dfx.x;  slx.x = cA ? ds.x : slx.x;
        tfx.y = cB ? tcur : tfx.y;  dfx.y = cB ? an.y : dfx.y;  slx.y = cB ? ds.y : slx.y;
        acc = an; tcur += 1.0f;
    }

    float oA, oB;
    if (tfx.x >= 0.0f) {
        const float sl = 0.2f * slx.x;
        const float ss = (sl >= 0.0f) ? fmaxf(sl, 1e-3f) : fminf(sl, -1e-3f);
        oA = ((tfx.x - (dfx.x - 0.5f) / ss) * 10.0f) / 1000.0f;
    } else oA = 1.2f;
    if (tfx.y >= 0.0f) {
        const float sl = 0.2f * slx.y;
        const float ss = (sl >= 0.0f) ? fmaxf(sl, 1e-3f) : fminf(sl, -1e-3f);
        oB = ((tfx.y - (dfx.y - 0.5f) / ss) * 10.0f) / 1000.0f;
    } else oB = 1.2f;
    out[jA] = oA;
    out[jB] = oB;
}

extern "C" void kernel_launch(void* const* d_in, const int* in_sizes, int n_in,
                              void* d_out, int out_size, void* d_ws, size_t ws_size,
                              hipStream_t stream) {
    const float* logits       = (const float*)d_in[0];
    const float* input_scale  = (const float*)d_in[1];
    const float* leak         = (const float*)d_in[2];
    const float* self_excit   = (const float*)d_in[3];
    const float* inhibition   = (const float*)d_in[4];
    // d_in[5] = competition_gain: unused (MIX == 0.0)
    const float* noise_std    = (const float*)d_in[6];
    const float* evidence_w   = (const float*)d_in[7];
    const float* evidence_b   = (const float*)d_in[8];

    const int n = in_sizes[0];              // B*C = 262144
    const int threads = 256;
    const int blocks = (n + 2 * threads - 1) / (2 * threads);
    accrace_kernel<<<blocks, threads, 0, stream>>>(
        logits, input_scale, leak, self_excit, inhibition,
        noise_std, evidence_w, evidence_b, (float*)d_out, n);
}

// Round 7
// 89.476 us; speedup vs baseline: 2.9904x; 1.0465x over previous
//
#include <hip/hip_runtime.h>
#include <cstdint>

#define TSTEPS 120
#define KPAD   (TSTEPS + 4)

typedef unsigned int u32;

__device__ __forceinline__ u32 rotl32(u32 x, u32 r) { return (x << r) | (x >> (32u - r)); }

// Exact 4-lane butterflies via DPP quad_perm (no LDS/DS pipe).
// [1,0,3,2] = 0xB1 (xor 1), [2,3,0,1] = 0x4E (xor 2).
__device__ __forceinline__ float qxor1(float x) {
    return __int_as_float(__builtin_amdgcn_update_dpp(0, __float_as_int(x), 0xB1, 0xF, 0xF, true));
}
__device__ __forceinline__ float qxor2(float x) {
    return __int_as_float(__builtin_amdgcn_update_dpp(0, __float_as_int(x), 0x4E, 0xF, 0xF, true));
}

// softplus(x) = max(x,0) + log1p(exp(-|x|)) via raw v_exp_f32 / v_log_f32
__device__ __forceinline__ float softplus_s(float x) {
    const float LOG2E = 1.4426950408889634f, LN2 = 0.6931471805599453f;
    float e = __builtin_amdgcn_exp2f(-fabsf(x) * LOG2E);
    return fmaxf(x, 0.0f) + __builtin_amdgcn_logf(1.0f + e) * LN2;
}

// XLA ErfInv (Giles poly); rare |x|>0.99665 tail behind a wave-uniform branch.
__device__ __forceinline__ float erfinv_fast(float x) {
    const float LN2 = 0.6931471805599453f;
    float t = __builtin_fmaf(-x, x, 1.0f);
    float w = __builtin_amdgcn_logf(t) * (-LN2);
    float wa = w - 2.5f;
    float p = 2.81022636e-08f;
    p = fmaf(p, wa, 3.43273939e-07f);
    p = fmaf(p, wa, -3.5233877e-06f);
    p = fmaf(p, wa, -4.39150654e-06f);
    p = fmaf(p, wa, 0.00021858087f);
    p = fmaf(p, wa, -0.00125372503f);
    p = fmaf(p, wa, -0.00417768164f);
    p = fmaf(p, wa, 0.246640727f);
    p = fmaf(p, wa, 1.50140941f);
    if (__any(w >= 5.0f)) {
        float wb = __builtin_amdgcn_sqrtf(w) - 3.0f;
        float q = -0.000200214257f;
        q = fmaf(q, wb, 0.000100950558f);
        q = fmaf(q, wb, 0.00134934322f);
        q = fmaf(q, wb, -0.00367342844f);
        q = fmaf(q, wb, 0.00573950773f);
        q = fmaf(q, wb, -0.0076224613f);
        q = fmaf(q, wb, 0.00943887047f);
        q = fmaf(q, wb, 1.00167406f);
        q = fmaf(q, wb, 2.83297682f);
        p = (w < 5.0f) ? p : q;
    }
    return p * x;
}

// Threefry-2x32, 20 rounds, counter (0,c), folded o0^o1 (partitionable bits).
// k0,k1,ks2,i1..i5 are wave-uniform SGPRs -> key schedule co-issues on SALU.
__device__ __forceinline__ u32 tf_one(u32 k0, u32 k1, u32 ks2,
                                      u32 i1, u32 i2, u32 i3, u32 i4, u32 i5,
                                      u32 c) {
    u32 x0 = k0, x1 = c + k1;
#define TF_R(r) { x0 += x1; x1 = rotl32(x1, (r)); x1 ^= x0; }
    TF_R(13u) TF_R(15u) TF_R(26u) TF_R(6u)
    x0 += k1;  x1 += i1;
    TF_R(17u) TF_R(29u) TF_R(16u) TF_R(24u)
    x0 += ks2; x1 += i2;
    TF_R(13u) TF_R(15u) TF_R(26u) TF_R(6u)
    x0 += k0;  x1 += i3;
    TF_R(17u) TF_R(29u) TF_R(16u) TF_R(24u)
    x0 += k1;  x1 += i4;
    TF_R(13u) TF_R(15u) TF_R(26u) TF_R(6u)
    x0 += ks2; x1 += i5;
#undef TF_R
    return x0 ^ x1;
}

#define TF_STEP(kv, out_bits)                                                  \
    {                                                                          \
        u32 k0_ = (u32)__builtin_amdgcn_readfirstlane((int)(kv).x);            \
        u32 k1_ = (u32)__builtin_amdgcn_readfirstlane((int)(kv).y);            \
        u32 ks2_ = k0_ ^ k1_ ^ 0x1BD11BDAu;                                    \
        out_bits = tf_one(k0_, k1_, ks2_, ks2_ + 1u, k0_ + 2u, k1_ + 3u,       \
                          ks2_ + 4u, k0_ + 5u, ctr);                           \
    }

__global__ __launch_bounds__(256, 4) void accrace_kernel(
    const float* __restrict__ logits,
    const float* __restrict__ g_input_scale,
    const float* __restrict__ g_leak,
    const float* __restrict__ g_se,
    const float* __restrict__ g_inhib,
    const float* __restrict__ g_nstd,
    const float* __restrict__ g_ew,
    const float* __restrict__ g_eb,
    float* __restrict__ out, int n)
{
    // split keys: keys[t] = threefry2x32((0,42),(0,t)), both words.
    // Padded to KPAD so loop prefetch needs no clamp (extra entries harmless).
    __shared__ uint2 kw[KPAD];
    const int tid = threadIdx.x;
    if (tid < KPAD) {
        const u32 k0 = 0u, k1 = 42u;
        const u32 ks2 = k0 ^ k1 ^ 0x1BD11BDAu;
        u32 x0 = k0, x1 = (u32)tid + k1;
#define TF_R(r) { x0 += x1; x1 = rotl32(x1, (r)); x1 ^= x0; }
        TF_R(13u) TF_R(15u) TF_R(26u) TF_R(6u)
        x0 += k1;  x1 += ks2 + 1u;
        TF_R(17u) TF_R(29u) TF_R(16u) TF_R(24u)
        x0 += ks2; x1 += k0 + 2u;
        TF_R(13u) TF_R(15u) TF_R(26u) TF_R(6u)
        x0 += k0;  x1 += k1 + 3u;
        TF_R(17u) TF_R(29u) TF_R(16u) TF_R(24u)
        x0 += k1;  x1 += ks2 + 4u;
        TF_R(13u) TF_R(15u) TF_R(26u) TF_R(6u)
        x0 += ks2; x1 += k0 + 5u;
#undef TF_R
        kw[tid] = make_uint2(x0, x1);
    }
    __syncthreads();

    const int j = blockIdx.x * 256 + tid;      // one element per thread
    if (j >= n) return;
    const int c = tid & 3;

    const float input_scale = g_input_scale[0];
    const float lkc   = softplus_s(g_leak[c]);
    const float sec   = softplus_s(g_se[c]);
    const float inhib = softplus_s(g_inhib[0]);
    const float nstd  = softplus_s(g_nstd[0]);
    const float ew = g_ew[0], eb = g_eb[0];

    const float gain   = sec + inhib - lkc;                // drive fold
    const float minhib = -inhib;
    const float SQ2N   = 1.41421356237309515f * nstd;      // noise fold
    const float LO     = -0.99999994f;                     // nextafter(-1,0)

    // evidence: exact 4-lane mean over the row's classes, via DPP
    const float xs = logits[j] * input_scale;
    float m = xs + qxor1(xs); m = (m + qxor2(m)) * 0.25f;
    const float evd = softplus_s(xs - m) * ew + eb;

    const u32 ctr = (u32)j;

    // software pipeline: bits for step t computed during step t-1;
    // keys double-prefetched (kcur = key[t+1], knext = key[t+2]).
    u32 nb;
    { uint2 k0v = kw[0]; TF_STEP(k0v, nb); }
    uint2 kcur  = kw[1];
    uint2 knext = kw[2];

    float acc = 0.0f, dfx = 0.0f, slx = 0.0f;
    int idxv = -1;

#pragma unroll 2
    for (int t = 0; t < TSTEPS; ++t) {
        const u32 bits = nb;
        TF_STEP(kcur, nb);                      // bits for step t+1 (indep chain)
        kcur = knext;
        knext = kw[t + 3];                      // padded -> always in bounds

        // per-row total (exact 4-lane tree via DPP)
        float s1  = acc + qxor1(acc);
        float tot = s1 + qxor2(s1);

        // bits -> uniform(-1,1) -> normal
        const float F = __uint_as_float((bits >> 9) | 0x3F800000u);   // [1,2)
        const float u = fmaxf(fmaf(F, 2.0f, -3.0f), LO);              // 2F-3 == (F-1)*2+LO to 1ulp
        const float nz = erfinv_fast(u) * SQ2N;

        // drive = evd + gain*acc - inhib*tot ; ds = softplus(drive+nz) - acc
        const float dr = fmaf(acc, gain, fmaf(tot, minhib, evd));
        const float sp = softplus_s(dr + nz);
        const float ds = sp - acc;
        const float an = fmaxf(fmaf(ds, 0.2f, acc), 0.0f);

        const bool cr = (idxv < 0) & (an > 0.5f);
        idxv = cr ? t : idxv;
        dfx  = cr ? an : dfx;
        slx  = cr ? ds : slx;
        acc = an;
    }

    float o = 1.2f;                             // never crossed: T*DT ms -> s
    if (idxv >= 0) {
        const float sl = 0.2f * slx;
        const float ss = (sl >= 0.0f) ? fmaxf(sl, 1e-3f) : fminf(sl, -1e-3f);
        o = (((float)idxv - (dfx - 0.5f) / ss) * 10.0f) / 1000.0f;
    }
    out[j] = o;
}

extern "C" void kernel_launch(void* const* d_in, const int* in_sizes, int n_in,
                              void* d_out, int out_size, void* d_ws, size_t ws_size,
                              hipStream_t stream) {
    const float* logits       = (const float*)d_in[0];
    const float* input_scale  = (const float*)d_in[1];
    const float* leak         = (const float*)d_in[2];
    const float* self_excit   = (const float*)d_in[3];
    const float* inhibition   = (const float*)d_in[4];
    // d_in[5] = competition_gain: unused (MIX == 0.0)
    const float* noise_std    = (const float*)d_in[6];
    const float* evidence_w   = (const float*)d_in[7];
    const float* evidence_b   = (const float*)d_in[8];

    const int n = in_sizes[0];              // B*C = 262144
    const int threads = 256;
    const int blocks = (n + threads - 1) / threads;   // 1024 -> 4 waves/SIMD
    accrace_kernel<<<blocks, threads, 0, stream>>>(
        logits, input_scale, leak, self_excit, inhibition,
        noise_std, evidence_w, evidence_b, (float*)d_out, n);
}

// Round 8
// 88.734 us; speedup vs baseline: 3.0154x; 1.0084x over previous
//
#include <hip/hip_runtime.h>
#include <cstdint>

#define TSTEPS 120
#define KPAD   (TSTEPS + 4)

typedef unsigned int u32;

// ---------- compile-time threefry: the 120 split keys are constants ----------
constexpr u32 rotl_c(u32 x, u32 r) { return (x << r) | (x >> (32u - r)); }

struct KeyTab { u32 w[KPAD][2]; };

constexpr KeyTab make_tab() {
    KeyTab kt{};
    for (int t = 0; t < KPAD; ++t) {
        const u32 k0 = 0u, k1 = 42u, ks2 = k0 ^ k1 ^ 0x1BD11BDAu;
        u32 x0 = k0, x1 = (u32)t + k1;
        const u32 rA[4] = {13u, 15u, 26u, 6u};
        const u32 rB[4] = {17u, 29u, 16u, 24u};
        for (int g = 0; g < 5; ++g) {
            const u32* rr = (g % 2 == 0) ? rA : rB;
            for (int i = 0; i < 4; ++i) { x0 += x1; x1 = rotl_c(x1, rr[i]); x1 ^= x0; }
            switch (g) {
                case 0: x0 += k1;  x1 += ks2 + 1u; break;
                case 1: x0 += ks2; x1 += k0 + 2u;  break;
                case 2: x0 += k0;  x1 += k1 + 3u;  break;
                case 3: x0 += k1;  x1 += ks2 + 4u; break;
                case 4: x0 += ks2; x1 += k0 + 5u;  break;
            }
        }
        kt.w[t][0] = x0; kt.w[t][1] = x1;
    }
    return kt;
}

__constant__ KeyTab KT = make_tab();   // 992 B, scalar-cached, s_load access

__device__ __forceinline__ u32 rotl32(u32 x, u32 r) { return (x << r) | (x >> (32u - r)); }

// Exact 4-lane butterflies via DPP quad_perm. [1,0,3,2]=0xB1 (xor1), [2,3,0,1]=0x4E (xor2).
__device__ __forceinline__ float qxor1(float x) {
    return __int_as_float(__builtin_amdgcn_update_dpp(0, __float_as_int(x), 0xB1, 0xF, 0xF, true));
}
__device__ __forceinline__ float qxor2(float x) {
    return __int_as_float(__builtin_amdgcn_update_dpp(0, __float_as_int(x), 0x4E, 0xF, 0xF, true));
}

// softplus(x) = max(x,0) + log1p(exp(-|x|)) via raw v_exp_f32 / v_log_f32
__device__ __forceinline__ float softplus_s(float x) {
    const float LOG2E = 1.4426950408889634f, LN2 = 0.6931471805599453f;
    float e = __builtin_amdgcn_exp2f(-fabsf(x) * LOG2E);
    return fmaxf(x, 0.0f) + __builtin_amdgcn_logf(1.0f + e) * LN2;
}

// XLA ErfInv (Giles poly); rare |x|>0.99665 tail behind a wave-uniform branch.
__device__ __forceinline__ float erfinv_fast(float x) {
    const float LN2 = 0.6931471805599453f;
    float t = __builtin_fmaf(-x, x, 1.0f);
    float w = __builtin_amdgcn_logf(t) * (-LN2);
    float wa = w - 2.5f;
    float p = 2.81022636e-08f;
    p = fmaf(p, wa, 3.43273939e-07f);
    p = fmaf(p, wa, -3.5233877e-06f);
    p = fmaf(p, wa, -4.39150654e-06f);
    p = fmaf(p, wa, 0.00021858087f);
    p = fmaf(p, wa, -0.00125372503f);
    p = fmaf(p, wa, -0.00417768164f);
    p = fmaf(p, wa, 0.246640727f);
    p = fmaf(p, wa, 1.50140941f);
    if (__any(w >= 5.0f)) {
        float wb = __builtin_amdgcn_sqrtf(w) - 3.0f;
        float q = -0.000200214257f;
        q = fmaf(q, wb, 0.000100950558f);
        q = fmaf(q, wb, 0.00134934322f);
        q = fmaf(q, wb, -0.00367342844f);
        q = fmaf(q, wb, 0.00573950773f);
        q = fmaf(q, wb, -0.0076224613f);
        q = fmaf(q, wb, 0.00943887047f);
        q = fmaf(q, wb, 1.00167406f);
        q = fmaf(q, wb, 2.83297682f);
        p = (w < 5.0f) ? p : q;
    }
    return p * x;
}

// Threefry-2x32, 20 rounds, counter (0,c), folded o0^o1 (partitionable bits).
// Keys come from __constant__ -> SGPRs; key schedule is SALU (co-issues).
__device__ __forceinline__ u32 tf_bits(int t, u32 c) {
    const u32 k0 = KT.w[t][0], k1 = KT.w[t][1];
    const u32 ks2 = k0 ^ k1 ^ 0x1BD11BDAu;
    const u32 i1 = ks2 + 1u, i2 = k0 + 2u, i3 = k1 + 3u, i4 = ks2 + 4u, i5 = k0 + 5u;
    u32 x0 = k0, x1 = c + k1;
#define TF_R(r) { x0 += x1; x1 = rotl32(x1, (r)); x1 ^= x0; }
    TF_R(13u) TF_R(15u) TF_R(26u) TF_R(6u)
    x0 += k1;  x1 += i1;
    TF_R(17u) TF_R(29u) TF_R(16u) TF_R(24u)
    x0 += ks2; x1 += i2;
    TF_R(13u) TF_R(15u) TF_R(26u) TF_R(6u)
    x0 += k0;  x1 += i3;
    TF_R(17u) TF_R(29u) TF_R(16u) TF_R(24u)
    x0 += k1;  x1 += i4;
    TF_R(13u) TF_R(15u) TF_R(26u) TF_R(6u)
    x0 += ks2; x1 += i5;
#undef TF_R
    return x0 ^ x1;
}

__global__ __launch_bounds__(256, 4) void accrace_kernel(
    const float* __restrict__ logits,
    const float* __restrict__ g_input_scale,
    const float* __restrict__ g_leak,
    const float* __restrict__ g_se,
    const float* __restrict__ g_inhib,
    const float* __restrict__ g_nstd,
    const float* __restrict__ g_ew,
    const float* __restrict__ g_eb,
    float* __restrict__ out, int n)
{
    const int tid = threadIdx.x;
    const int j = blockIdx.x * 256 + tid;      // one element per thread
    if (j >= n) return;
    const int c = tid & 3;

    const float input_scale = g_input_scale[0];
    const float lkc   = softplus_s(g_leak[c]);
    const float sec   = softplus_s(g_se[c]);
    const float inhib = softplus_s(g_inhib[0]);
    const float nstd  = softplus_s(g_nstd[0]);
    const float ew = g_ew[0], eb = g_eb[0];

    const float gain   = sec + inhib - lkc;                // drive fold
    const float minhib = -inhib;
    const float SQ2N   = 1.41421356237309515f * nstd;      // noise fold
    const float LO     = -0.99999994f;                     // nextafter(-1,0)

    // evidence: exact 4-lane mean over the row's classes, via DPP
    const float xs = logits[j] * input_scale;
    float m = xs + qxor1(xs); m = (m + qxor2(m)) * 0.25f;
    const float evd = softplus_s(xs - m) * ew + eb;

    const u32 ctr = (u32)j;

    // two-deep software pipeline:
    //   nz    = finished noise for step t   (computed during step t-1)
    //   bitsa = raw bits for step t+1       (computed during step t-1)
    float nz;
    u32 bitsa;
    {
        const u32 b0 = tf_bits(0, ctr);
        const float F0 = __uint_as_float((b0 >> 9) | 0x3F800000u);
        const float u0 = fmaxf(fmaf(F0, 2.0f, -3.0f), LO);
        nz = erfinv_fast(u0) * SQ2N;
        bitsa = tf_bits(1, ctr);
    }

    float acc = 0.0f, dfx = 0.0f, slx = 0.0f;
    int idxv = -1;

#pragma unroll 4
    for (int t = 0; t < TSTEPS; ++t) {
        // ---- dependent (loop-carried) chain: short ----
        float s1  = acc + qxor1(acc);
        float tot = s1 + qxor2(s1);
        const float dr = fmaf(acc, gain, fmaf(tot, minhib, evd));
        const float sp = softplus_s(dr + nz);
        const float ds = sp - acc;
        const float an = fmaxf(fmaf(ds, 0.2f, acc), 0.0f);

        const bool cr = (idxv < 0) & (an > 0.5f);
        idxv = cr ? t : idxv;
        dfx  = cr ? an : dfx;
        slx  = cr ? ds : slx;
        acc = an;

        // ---- ahead streams (independent ILP fodder) ----
        const float F = __uint_as_float((bitsa >> 9) | 0x3F800000u);  // [1,2)
        const float u = fmaxf(fmaf(F, 2.0f, -3.0f), LO);              // (-1,1)
        nz = erfinv_fast(u) * SQ2N;                                   // noise for t+1
        bitsa = tf_bits(t + 2, ctr);                                  // bits for t+2 (KPAD-padded)
    }

    float o = 1.2f;                             // never crossed: T*DT ms -> s
    if (idxv >= 0) {
        const float sl = 0.2f * slx;
        const float ss = (sl >= 0.0f) ? fmaxf(sl, 1e-3f) : fminf(sl, -1e-3f);
        o = (((float)idxv - (dfx - 0.5f) / ss) * 10.0f) / 1000.0f;
    }
    out[j] = o;
}

extern "C" void kernel_launch(void* const* d_in, const int* in_sizes, int n_in,
                              void* d_out, int out_size, void* d_ws, size_t ws_size,
                              hipStream_t stream) {
    const float* logits       = (const float*)d_in[0];
    const float* input_scale  = (const float*)d_in[1];
    const float* leak         = (const float*)d_in[2];
    const float* self_excit   = (const float*)d_in[3];
    const float* inhibition   = (const float*)d_in[4];
    // d_in[5] = competition_gain: unused (MIX == 0.0)
    const float* noise_std    = (const float*)d_in[6];
    const float* evidence_w   = (const float*)d_in[7];
    const float* evidence_b   = (const float*)d_in[8];

    const int n = in_sizes[0];              // B*C = 262144
    const int threads = 256;
    const int blocks = (n + threads - 1) / threads;   // 1024 -> 4 waves/SIMD
    accrace_kernel<<<blocks, threads, 0, stream>>>(
        logits, input_scale, leak, self_excit, inhibition,
        noise_std, evidence_w, evidence_b, (float*)d_out, n);
}